// Round 1
// 72.132 us; speedup vs baseline: 1.0041x; 1.0041x over previous
//
#include <hip/hip_runtime.h>
#include <math.h>

#define BB 4
#define NN 4096
#define MM 512
#define PTS 8                  // point-slots per block
#define NPT 4                  // points per thread = 2 packed float2 groups
#define CHUNKS 64              // m-chunks
#define MCHUNK (MM / CHUNKS)   // 8 triangles per chunk
#define TPB 512

typedef float v2 __attribute__((ext_vector_type(2)));

__device__ __forceinline__ v2 pfma(v2 a, v2 b, v2 c) {
    return __builtin_elementwise_fma(a, b, c);   // -> v_pk_fma_f32 on gfx950
}
__device__ __forceinline__ v2 pmin(v2 a, v2 b) { return __builtin_elementwise_min(a, b); }
__device__ __forceinline__ v2 pmax(v2 a, v2 b) { return __builtin_elementwise_max(a, b); }
__device__ __forceinline__ v2 pclip01(v2 x) { return pmin(pmax(x, (v2)0.0f), (v2)1.0f); }

// reference _safe_div guard + hw rcp (~1 ulp) -- relative-class error, argmin-safe (R4-R7 validated)
__device__ __forceinline__ float safercp(float y) {
    float yy = (fabsf(y) < 1e-12f) ? 1.0f : y;
    return __builtin_amdgcn_rcpf(yy);
}

// exact IEEE version for phase-2 (matches reference bit-order, validated R1/R3/R6/R7)
__device__ __forceinline__ float safediv(float x, float y) {
    float yy = (fabsf(y) < 1e-12f) ? 1.0f : y;
    return x / yy;
}

__device__ __forceinline__ float clip01s(float x) {
    return fminf(fmaxf(x, 0.0f), 1.0f);
}

// Phase 2: exact reference-ordered Ericson for ONE pair (R1-validated numerics).
__device__ void exact_pair(float px, float py, float pz,
                           float ax, float ay, float az,
                           float bx, float by, float bz,
                           float cx, float cy, float cz,
                           float* dist2_out, int* reg_out) {
#pragma clang fp contract(off)
    const float abx = bx-ax, aby = by-ay, abz = bz-az;
    const float acx = cx-ax, acy = cy-ay, acz = cz-az;
    const float cbx = cx-bx, cby = cy-by, cbz = cz-bz;
    const float apx = px-ax, apy = py-ay, apz = pz-az;
    const float bpx = px-bx, bpy = py-by, bpz = pz-bz;
    const float cpx = px-cx, cpy = py-cy, cpz = pz-cz;

    const float d1 = abx*apx + aby*apy + abz*apz;
    const float d2 = acx*apx + acy*apy + acz*apz;
    const float d3 = abx*bpx + aby*bpy + abz*bpz;
    const float d4 = acx*bpx + acy*bpy + acz*bpz;
    const float d5 = abx*cpx + aby*cpy + abz*cpz;
    const float d6 = acx*cpx + acy*cpy + acz*cpz;

    const float vc = d1*d4 - d3*d2;
    const float vb = d5*d2 - d1*d6;
    const float va = d3*d6 - d5*d4;

    const float v_ab = clip01s(safediv(d1, d1 - d3));
    const float v_ac = clip01s(safediv(d2, d2 - d6));
    const float t43 = d4 - d3;
    const float t56 = d5 - d6;
    const float v_bc = clip01s(safediv(t43, t43 + t56));
    const float denom = va + vb + vc;
    const float v_f = safediv(vb, denom);
    const float w_f = safediv(vc, denom);

    float qx = ax + v_f*abx + w_f*acx;
    float qy = ay + v_f*aby + w_f*acy;
    float qz = az + v_f*abz + w_f*acz;
    int reg = 6;
    const bool c_bc = (va <= 0.0f) && (t43 >= 0.0f) && (t56 >= 0.0f);
    if (c_bc) { qx = bx + v_bc*cbx; qy = by + v_bc*cby; qz = bz + v_bc*cbz; reg = 5; }
    const bool c_ac = (vb <= 0.0f) && (d2 >= 0.0f) && (d6 <= 0.0f);
    if (c_ac) { qx = ax + v_ac*acx; qy = ay + v_ac*acy; qz = az + v_ac*acz; reg = 4; }
    const bool c_c = (d6 >= 0.0f) && (d5 <= d6);
    if (c_c) { qx = cx; qy = cy; qz = cz; reg = 2; }
    const bool c_ab = (vc <= 0.0f) && (d1 >= 0.0f) && (d3 <= 0.0f);
    if (c_ab) { qx = ax + v_ab*abx; qy = ay + v_ab*aby; qz = az + v_ab*abz; reg = 3; }
    const bool c_b = (d3 >= 0.0f) && (d4 <= d3);
    if (c_b) { qx = bx; qy = by; qz = bz; reg = 1; }
    const bool c_a = (d1 <= 0.0f) && (d2 <= 0.0f);
    if (c_a) { qx = ax; qy = ay; qz = az; reg = 0; }

    const float dx = px - qx;
    const float dy = py - qy;
    const float dz = pz - qz;
    *dist2_out = dx*dx + dy*dy + dz*dz;
    *reg_out = reg;
}

// __launch_bounds__(512, 4): 4 waves/EU x 4 EU = 16 waves/CU = 2 blocks/CU PINNED,
// caps VGPR alloc at 128/wave. Without the 2nd arg the allocator may exceed 128
// VGPRs -> occupancy silently halves to 1 block/CU (R8 experiment).
__global__ __launch_bounds__(TPB, 4) void tridist_kernel(
    const float* __restrict__ xyz1, const float* __restrict__ tri1,
    const float* __restrict__ tri2, const float* __restrict__ tri3,
    float* __restrict__ out)
{
    // 6 float4 per record:
    //  r0[a.xyz  nna(-n.a)] r1[ab.xyz rab2] r2[ac.xyz rac2] r3[cb.xyz rcb2]
    //  r4[n.xyz  abac]      r5[naba(-ab.a) naca(-ac.a) ab2 ac2]
    // +1 float4 pad per group of 8 records (49 float4/group): the 8 records a
    // wave touches start on banks {0,4,...,28} -> conflict-free (R7-validated).
    __shared__ float4 sT[(MM / 8) * 49];      // 50176 B
    __shared__ float  sPd[NPT][64];
    __shared__ int    sPj[NPT][64];           // total 52224 B -> 2 blocks/CU

    const int t  = threadIdx.x;
    const int b  = blockIdx.x >> 7;          // 128 blocks per batch
    const int pb = blockIdx.x & 127;
    const int pt = t & (PTS - 1);
    const int ch = t >> 3;                   // chunk [0,64)

    // ---- point loads hoisted ABOVE staging: global-load latency overlaps the
    // staging compute + barrier (no dependence on LDS) ----
    v2 Px[2], Py[2], Pz[2];
#pragma unroll
    for (int np = 0; np < NPT; ++np) {
        const int gi = b * NN + pb * 32 + np * PTS + pt;
        const float* pp = &xyz1[(size_t)gi * 3];
        Px[np >> 1][np & 1] = pp[0];
        Py[np >> 1][np & 1] = pp[1];
        Pz[np >> 1][np & 1] = pp[2];
    }

    // ---- stage + per-triangle precompute (one thread per triangle, TPB==MM) ----
    {
        const int jj = t;
        const float* g1 = tri1 + ((size_t)b * MM + jj) * 3;
        const float* g2 = tri2 + ((size_t)b * MM + jj) * 3;
        const float* g3 = tri3 + ((size_t)b * MM + jj) * 3;
        const float ax = g1[0], ay = g1[1], az = g1[2];
        const float bx = g2[0], by = g2[1], bz = g2[2];
        const float cx = g3[0], cy = g3[1], cz = g3[2];
        const float abx = bx-ax, aby = by-ay, abz = bz-az;
        const float acx = cx-ax, acy = cy-ay, acz = cz-az;
        const float cbx = cx-bx, cby = cy-by, cbz = cz-bz;
        const float aba  = fmaf(abz, az, fmaf(aby, ay, abx*ax));
        const float aca  = fmaf(acz, az, fmaf(acy, ay, acx*ax));
        const float ab2  = fmaf(abz, abz, fmaf(aby, aby, abx*abx));   // == d1-d3
        const float ac2  = fmaf(acz, acz, fmaf(acy, acy, acx*acx));   // == d2-d6
        const float cb2  = fmaf(cbz, cbz, fmaf(cby, cby, cbx*cbx));
        const float abac = fmaf(abz, acz, fmaf(aby, acy, abx*acx));
        const float nrx = fmaf(aby, acz, -(abz*acy));
        const float nry = fmaf(abz, acx, -(abx*acz));
        const float nrz = fmaf(abx, acy, -(aby*acx));
        const float n2  = fmaf(nrz, nrz, fmaf(nry, nry, nrx*nrx));
        const float rn  = __builtin_amdgcn_rsqf(fmaxf(n2, 1e-30f));
        const float nx = nrx*rn, ny = nry*rn, nz = nrz*rn;
        const float nna = -fmaf(nz, az, fmaf(ny, ay, nx*ax));
        const int base = (jj >> 3) * 49 + (jj & 7) * 6;
        sT[base + 0] = make_float4(ax, ay, az, nna);
        sT[base + 1] = make_float4(abx, aby, abz, safercp(ab2));
        sT[base + 2] = make_float4(acx, acy, acz, safercp(ac2));
        sT[base + 3] = make_float4(cbx, cby, cbz, safercp(cb2));
        sT[base + 4] = make_float4(nx, ny, nz, abac);
        sT[base + 5] = make_float4(-aba, -aca, ab2, ac2);
    }
    __syncthreads();

    float bestd[NPT] = {INFINITY, INFINITY, INFINITY, INFINITY};
    int   bestj[NPT] = {0, 0, 0, 0};

    // ---- phase 1: packed min-form distance ----
    for (int i = 0; i < MCHUNK; ++i) {
        const int j = ch * MCHUNK + i;
        const int base = ch * 49 + i * 6;
        const float4 r0 = sT[base + 0];
        const float4 r1 = sT[base + 1];
        const float4 r2 = sT[base + 2];
        const float4 r3 = sT[base + 3];
        const float4 r4 = sT[base + 4];
        const float4 r5 = sT[base + 5];
        const float ax = r0.x, ay = r0.y, az = r0.z, nna = r0.w;
        const float abx = r1.x, aby = r1.y, abz = r1.z, rab2 = r1.w;
        const float acx = r2.x, acy = r2.y, acz = r2.z, rac2 = r2.w;
        const float cbx = r3.x, cby = r3.y, cbz = r3.z, rcb2 = r3.w;
        const float nx = r4.x, ny = r4.y, nz = r4.z, abac = r4.w;
        const float naba = r5.x, naca = r5.y, ab2 = r5.z, ac2 = r5.w;

#pragma unroll
        for (int g = 0; g < 2; ++g) {
            const v2 X = Px[g], Y = Py[g], Z = Pz[g];

            const v2 d1 = pfma((v2)abz, Z, pfma((v2)aby, Y, pfma((v2)abx, X, (v2)naba)));
            const v2 d2 = pfma((v2)acz, Z, pfma((v2)acy, Y, pfma((v2)acx, X, (v2)naca)));
            const v2 h  = pfma((v2)nz,  Z, pfma((v2)ny,  Y, pfma((v2)nx,  X, (v2)nna)));
            const v2 d3 = d1 - (v2)ab2;     // identity: d1-d3 == ab.ab
            const v2 d4 = d2 - (v2)abac;    // identity: ac.b - ac.a == ab.ac
            const v2 d5 = d1 - (v2)abac;    // identity: ab.c - ab.a == ab.ac
            const v2 d6 = d2 - (v2)ac2;     // identity: d2-d6 == ac.ac

            const v2 vc = pfma(d1, d4, -(d3*d2));
            const v2 vb = pfma(d5, d2, -(d1*d6));
            const v2 va = pfma(d3, d6, -(d5*d4));
            const v2 t43 = d4 - d3;

            const v2 v_ab = pclip01(d1 * (v2)rab2);
            const v2 v_ac = pclip01(d2 * (v2)rac2);
            const v2 v_bc = pclip01(t43 * (v2)rcb2);

            const v2 apx = X - (v2)ax, apy = Y - (v2)ay, apz = Z - (v2)az;
            const v2 bpx = apx - (v2)abx, bpy = apy - (v2)aby, bpz = apz - (v2)abz;

            v2 ex = pfma(-v_ab, (v2)abx, apx);
            v2 ey = pfma(-v_ab, (v2)aby, apy);
            v2 ez = pfma(-v_ab, (v2)abz, apz);
            const v2 dAB = pfma(ez, ez, pfma(ey, ey, ex*ex));
            ex = pfma(-v_ac, (v2)acx, apx);
            ey = pfma(-v_ac, (v2)acy, apy);
            ez = pfma(-v_ac, (v2)acz, apz);
            const v2 dAC = pfma(ez, ez, pfma(ey, ey, ex*ex));
            ex = pfma(-v_bc, (v2)cbx, bpx);
            ey = pfma(-v_bc, (v2)cby, bpy);
            ez = pfma(-v_bc, (v2)cbz, bpz);
            const v2 dBC = pfma(ez, ez, pfma(ey, ey, ex*ex));
            const v2 dF = h * h;

            const v2 mv   = pmin(pmin(va, vb), vc);
            const v2 dseg = pmin(pmin(dAB, dAC), dBC);

#pragma unroll
            for (int c = 0; c < 2; ++c) {
                const float dist2 = (mv[c] >= 0.0f) ? dF[c] : dseg[c];
                const int np = g * 2 + c;
                // strict < ascending j: first-occurrence tie-break like np.argmin
                if (dist2 < bestd[np]) { bestd[np] = dist2; bestj[np] = j; }
            }
        }
    }

    // ---- in-wave butterfly over the 8 chunks this wave holds ----
#pragma unroll
    for (int np = 0; np < NPT; ++np) {
        for (int off = 8; off <= 32; off <<= 1) {
            const float od = __shfl_xor(bestd[np], off, 64);
            const int   oj = __shfl_xor(bestj[np], off, 64);
            if (od < bestd[np] || (od == bestd[np] && oj < bestj[np])) {
                bestd[np] = od; bestj[np] = oj;
            }
        }
    }
    const int lane = t & 63;
    const int w    = t >> 6;                 // wave [0,8)
    if (lane < PTS) {
#pragma unroll
        for (int np = 0; np < NPT; ++np) {
            sPd[np][w * PTS + lane] = bestd[np];
            sPj[np][w * PTS + lane] = bestj[np];
        }
    }
    __syncthreads();

    // ---- final reduce + phase 2: exact recompute for the winner ----
    if (t < 32) {
        const int np = t >> 3;
        const int p  = t & 7;
        float bd = INFINITY; int bj = 0;
        for (int k = 0; k < 8; ++k) {        // waves ascend -> chunks ascend -> j ascends
            const float dk = sPd[np][k * PTS + p];
            const int   jk = sPj[np][k * PTS + p];
            if (dk < bd || (dk == bd && jk < bj)) { bd = dk; bj = jk; }
        }
        const float* g1 = tri1 + ((size_t)b * MM + bj) * 3;
        const float* g2 = tri2 + ((size_t)b * MM + bj) * 3;
        const float* g3 = tri3 + ((size_t)b * MM + bj) * 3;
        const int gidx = b * NN + pb * 32 + t;   // t == np*8 + p
        float dist2; int reg;
        exact_pair(xyz1[gidx*3+0], xyz1[gidx*3+1], xyz1[gidx*3+2],
                   g1[0], g1[1], g1[2],
                   g2[0], g2[1], g2[2],
                   g3[0], g3[1], g3[2],
                   &dist2, &reg);
        out[gidx]             = dist2;
        out[BB*NN + gidx]     = (float)reg;
        out[2*BB*NN + gidx]   = (float)bj;
    }
}

extern "C" void kernel_launch(void* const* d_in, const int* in_sizes, int n_in,
                              void* d_out, int out_size, void* d_ws, size_t ws_size,
                              hipStream_t stream) {
    const float* xyz1 = (const float*)d_in[0];
    const float* tri1 = (const float*)d_in[1];
    const float* tri2 = (const float*)d_in[2];
    const float* tri3 = (const float*)d_in[3];
    float* out = (float*)d_out;

    dim3 grid(BB * (NN / 32));    // 512 blocks -> 2 blocks/CU, 16 waves/CU
    dim3 block(TPB);              // 512 threads
    tridist_kernel<<<grid, block, 0, stream>>>(xyz1, tri1, tri2, tri3, out);
}